// Round 2
// baseline (201.596 us; speedup 1.0000x reference)
//
#include <hip/hip_runtime.h>
#include <float.h>

#define D    64
#define K    512
#define HW   4096      // 64*64
#define NPIX 131072    // 32*4096
#define KT   32

// ws layout:
// [0,    2048)          float ck[512]   (np-style sum(cb*cb, axis=0))
// [2048, 2048+4*NPIX)   int   idx[NPIX]

// c_k = np.sum(cb*cb, axis=0)[k]: outer-axis reduce -> SEQUENTIAL adds over d,
// each square rounded to f32 first. fp-contract off so e*e is not fused.
__global__ void vq_prep(const float* __restrict__ cb, float* __restrict__ ck) {
#pragma clang fp contract(off)
    const int k = threadIdx.x;
    float s = 0.f;
    for (int d = 0; d < D; ++d) {
        const float e  = cb[d * K + k];
        const float e2 = e * e;
        s = s + e2;
    }
    ck[k] = s;
}

__global__ __launch_bounds__(256) void vq_main(const float* __restrict__ enc,
        const float* __restrict__ cb, const float* __restrict__ ck,
        int* __restrict__ idx) {
    __shared__ float xs[D][256];   // 64 KB
    const int t = threadIdx.x;
    const int p = blockIdx.x * 256 + t;
    const int b = p >> 12;
    const int hw = p & 4095;
    const float* xp = enc + (size_t)b * (D * HW) + hw;
    #pragma unroll
    for (int d = 0; d < D; ++d) xs[d][t] = xp[(size_t)d * HW];
    __syncthreads();

    // t1 = np.sum(flat*flat, axis=1): numpy pairwise_sum, n=64 contiguous path:
    // 8 accumulators r[j] = a[j] + a[j+8] + ... + a[j+56] (sequential), then
    // ((r0+r1)+(r2+r3))+((r4+r5)+(r6+r7)). Squares pre-rounded, no fma fusing.
    float t1;
    {
#pragma clang fp contract(off)
        float r[8];
        #pragma unroll
        for (int j = 0; j < 8; ++j) {
            const float v = xs[j][t];
            r[j] = v * v;
        }
        #pragma unroll
        for (int i = 8; i < 64; i += 8) {
            #pragma unroll
            for (int j = 0; j < 8; ++j) {
                const float v  = xs[i + j][t];
                const float v2 = v * v;
                r[j] = r[j] + v2;
            }
        }
        t1 = ((r[0] + r[1]) + (r[2] + r[3])) + ((r[4] + r[5]) + (r[6] + r[7]));
    }

    float best = FLT_MAX;
    int besti = 0;
    for (int k0 = 0; k0 < K; k0 += KT) {
        // dot_k: sgemm semantics = single sequential fma chain over d (ascending)
        float acc[KT];
        #pragma unroll
        for (int j = 0; j < KT; ++j) acc[j] = 0.f;
        #pragma unroll 2
        for (int d = 0; d < D; ++d) {
            const float xv = xs[d][t];                 // ds_read, conflict-free
            const float* cbrow = cb + d * K + k0;      // wave-uniform -> s_load
            #pragma unroll
            for (int j = 0; j < KT; ++j)
                acc[j] = fmaf(xv, cbrow[j], acc[j]);
        }
        // dist = (t1 - 2*dot) + c, each op rounded f32 (2*dot is exact).
        {
#pragma clang fp contract(off)
            #pragma unroll
            for (int j = 0; j < KT; ++j) {
                const float u    = t1 - 2.0f * acc[j];
                const float dist = u + ck[k0 + j];
                if (dist < best) { best = dist; besti = k0 + j; }  // strict <: first occurrence
            }
        }
    }
    idx[p] = besti;
}

__global__ void vq_out(const float* __restrict__ cb, const int* __restrict__ idx,
                       float* __restrict__ out) {
    const int o = blockIdx.x * 256 + threadIdx.x;
    const int d = (o >> 12) & 63;
    const int bhw = ((o >> 18) << 12) | (o & 4095);
    out[o] = cb[d * K + idx[bhw]];
}

extern "C" void kernel_launch(void* const* d_in, const int* in_sizes, int n_in,
                              void* d_out, int out_size, void* d_ws, size_t ws_size,
                              hipStream_t stream) {
    const float* enc = (const float*)d_in[0];
    const float* cb  = (const float*)d_in[1];
    float* out = (float*)d_out;
    char* ws = (char*)d_ws;
    float* ck  = (float*)ws;
    int*   idx = (int*)(ws + 2048);

    vq_prep<<<1, K, 0, stream>>>(cb, ck);
    vq_main<<<NPIX / 256, 256, 0, stream>>>(enc, cb, ck, idx);
    vq_out<<<out_size / 256, 256, 0, stream>>>(cb, idx, out);
}

// Round 3
// 174.431 us; speedup vs baseline: 1.1557x; 1.1557x over previous
//
#include <hip/hip_runtime.h>
#include <float.h>

#define D    64
#define K    512
#define HW   4096      // 64*64
#define NPIX 131072    // 32*4096
#define KT   32

// ws layout:
// [0,    2048)          float ck[512]   (np-style sum(cb*cb, axis=0))
// [2048, 2048+4*NPIX)   int   idx[NPIX]

// c_k = np.sum(cb*cb, axis=0)[k]: outer-axis reduce -> SEQUENTIAL adds over d,
// each square rounded to f32 first. fp-contract off so e*e is not fused.
__global__ void vq_prep(const float* __restrict__ cb, float* __restrict__ ck) {
#pragma clang fp contract(off)
    const int k = threadIdx.x;
    float s = 0.f;
    for (int d = 0; d < D; ++d) {
        const float e  = cb[d * K + k];
        const float e2 = e * e;
        s = s + e2;
    }
    ck[k] = s;
}

// Split-K x2: block = 128 pixels. Waves 0,1 -> codes [0,256); waves 2,3 -> [256,512).
// x[64] lives in VGPRs; cb rows are wave-uniform -> s_load; combine via 1KB LDS.
__global__ __launch_bounds__(256, 4) void vq_main(const float* __restrict__ enc,
        const float* __restrict__ cb, const float* __restrict__ ck,
        int* __restrict__ idx) {
    const int t = threadIdx.x;
    const int lane = t & 63;
    // force wave-uniformity into SGPRs so cb addressing stays scalar
    const int wu    = __builtin_amdgcn_readfirstlane(t >> 6);   // wave id 0..3
    const int pg    = wu & 1;        // pixel subgroup (which 64 pixels)
    const int khalf = wu >> 1;       // code half

    const int p  = blockIdx.x * 128 + pg * 64 + lane;
    const int b  = p >> 12;
    const int hw = p & 4095;
    const float* xp = enc + (size_t)b * (D * HW) + hw;

    float x[D];
    #pragma unroll
    for (int d = 0; d < D; ++d) x[d] = xp[(size_t)d * HW];

    // t1 = np.sum(flat*flat, axis=1): numpy pairwise, n=64 contiguous path:
    // 8 accumulators r[j] = sum_i a[8i+j] (sequential), then
    // ((r0+r1)+(r2+r3))+((r4+r5)+(r6+r7)). Squares pre-rounded, no fma fusing.
    float t1;
    {
#pragma clang fp contract(off)
        float r[8];
        #pragma unroll
        for (int j = 0; j < 8; ++j) r[j] = x[j] * x[j];
        #pragma unroll
        for (int i = 8; i < 64; i += 8) {
            #pragma unroll
            for (int j = 0; j < 8; ++j) {
                const float v2 = x[i + j] * x[i + j];
                r[j] = r[j] + v2;
            }
        }
        t1 = ((r[0] + r[1]) + (r[2] + r[3])) + ((r[4] + r[5]) + (r[6] + r[7]));
    }

    float best = FLT_MAX;
    int besti = 0;
    const int kbase = khalf * (K / 2);
    for (int k0 = kbase; k0 < kbase + K / 2; k0 += KT) {
        // sgemm semantics: single sequential fma chain over d (ascending)
        float acc[KT];
        #pragma unroll
        for (int j = 0; j < KT; ++j) acc[j] = 0.f;
        #pragma unroll
        for (int d = 0; d < D; ++d) {
            const float xv = x[d];
            const float* cbrow = cb + d * K + k0;      // wave-uniform -> s_load
            #pragma unroll
            for (int j = 0; j < KT; ++j)
                acc[j] = fmaf(xv, cbrow[j], acc[j]);
        }
        // dist = (t1 - 2*dot) + c, each op rounded f32 (2*dot exact).
        {
#pragma clang fp contract(off)
            #pragma unroll
            for (int j = 0; j < KT; ++j) {
                const float u    = t1 - 2.0f * acc[j];
                const float dist = u + ck[k0 + j];
                if (dist < best) { best = dist; besti = k0 + j; }  // strict <: first occurrence
            }
        }
    }

    // combine halves: half-1 publishes, half-0 merges (ties -> lower k = half-0)
    __shared__ float bv[128];
    __shared__ int   bi[128];
    const int slot = pg * 64 + lane;
    if (khalf == 1) { bv[slot] = best; bi[slot] = besti; }
    __syncthreads();
    if (khalf == 0) {
        const float ov = bv[slot];
        const int   oi = bi[slot];
        if (ov < best) { best = ov; besti = oi; }
        idx[p] = besti;
    }
}

__global__ void vq_out(const float* __restrict__ cb, const int* __restrict__ idx,
                       float* __restrict__ out) {
    const int o = blockIdx.x * 256 + threadIdx.x;
    const int d = (o >> 12) & 63;
    const int bhw = ((o >> 18) << 12) | (o & 4095);
    out[o] = cb[d * K + idx[bhw]];
}

extern "C" void kernel_launch(void* const* d_in, const int* in_sizes, int n_in,
                              void* d_out, int out_size, void* d_ws, size_t ws_size,
                              hipStream_t stream) {
    const float* enc = (const float*)d_in[0];
    const float* cb  = (const float*)d_in[1];
    float* out = (float*)d_out;
    char* ws = (char*)d_ws;
    float* ck  = (float*)ws;
    int*   idx = (int*)(ws + 2048);

    vq_prep<<<1, K, 0, stream>>>(cb, ck);
    vq_main<<<NPIX / 128, 256, 0, stream>>>(enc, cb, ck, idx);
    vq_out<<<out_size / 256, 256, 0, stream>>>(cb, idx, out);
}